// Round 1
// 282.818 us; speedup vs baseline: 1.7081x; 1.7081x over previous
//
#include <hip/hip_runtime.h>

// Problem constants
static constexpr int Bn  = 64;     // batch
static constexpr int T   = 2048;   // angles
static constexpr int NA  = 256;    // atoms
static constexpr int DA  = 256;    // d_atom (K1)
static constexpr int DH  = 512;    // d_hid  (N1 / K2)
static constexpr int DO  = 256;    // d_out  (N2)
static constexpr int M   = Bn * T;         // 131072 rows
static constexpr int NBS = M / 128;        // 1024 stat blocks
static constexpr int NBC = M / 64;         // 2048 output blocks

typedef __attribute__((ext_vector_type(4))) float  f32x4;
typedef __attribute__((ext_vector_type(8))) __bf16 bf16x8;
typedef __attribute__((ext_vector_type(8))) short  short8;

__device__ __forceinline__ unsigned short f2bf(float f) {
  union { float f; unsigned u; } v; v.f = f;
  unsigned u = v.u + 0x7FFFu + ((v.u >> 16) & 1u);   // RNE
  return (unsigned short)(u >> 16);
}
__device__ __forceinline__ float bf2f(unsigned short b) {
  union { unsigned u; float f; } v; v.u = ((unsigned)b) << 16;
  return v.f;
}

// async global->LDS, 16B per lane; lds ptr must be wave-uniform base
__device__ __forceinline__ void gl_lds16(const void* g, void* l) {
  __builtin_amdgcn_global_load_lds(
      (const __attribute__((address_space(1))) unsigned int*)g,
      (__attribute__((address_space(3))) unsigned int*)l, 16, 0, 0);
}

// ---------------------------------------------------------------------------
// prep: W1 [256x512] f32 -> W1T [512][256] bf16 ; W2 [512x256] f32 -> W2T [256][512] bf16
// ---------------------------------------------------------------------------
__global__ void prep_kernel(const float* __restrict__ W1, const float* __restrict__ W2,
                            unsigned short* __restrict__ W1T, unsigned short* __restrict__ W2T) {
  int id = blockIdx.x * 256 + threadIdx.x;           // 131072 threads
  {
    int n = id >> 8, k = id & 255;                   // W1T[n][k] = W1[k][n]
    W1T[id] = f2bf(W1[k * DH + n]);
  }
  {
    int n = id >> 9, k = id & 511;                   // W2T[n][k] = W2[k][n]
    W2T[id] = f2bf(W2[k * DO + n]);
  }
}

// ---------------------------------------------------------------------------
// kA: zW[b*NA+a][n] = (z @ W1) in bf16.  16384 x 512, K=256.
// grid: 512 blocks = 256 m-tiles x 2 n-halves, 256 threads (4 waves).
// wave w: rows 0..63 x cols [n0b + w*64, +64)
// ---------------------------------------------------------------------------
__global__ __launch_bounds__(256) void kA_zw(
    const float* __restrict__ z, const unsigned short* __restrict__ W1T,
    unsigned short* __restrict__ zW) {
  __shared__ __align__(16) unsigned short As[4][64][8];    // [kq][m][8]  4KB
  __shared__ __align__(16) unsigned short Bs[4][256][8];   // [kq][n][8] 16KB
  const int tid = threadIdx.x;
  const int bm = blockIdx.x >> 1, bn = blockIdx.x & 1;
  const int row0 = bm * 64, n0b = bn * 256;
  const int wave = tid >> 6, lane = tid & 63, ql = lane >> 4, r16 = lane & 15;
  const int am = tid >> 2, akq = tid & 3;                  // 4 threads/row, 8 floats each
  const float* zrow = z + (size_t)(row0 + am) * DA + akq * 8;

  f32x4 acc[4][4] = {};

  for (int s = 0; s < 8; ++s) {
    const int k0 = s * 32;
    // B: async stage W1T[n0b..n0b+256][k0..k0+32] -> Bs[kq][n][8]
#pragma unroll
    for (int i = 0; i < 4; ++i)
      gl_lds16(W1T + (size_t)(n0b + tid) * DA + k0 + i * 8,
               (unsigned short*)Bs + (size_t)(i * 256 + (tid & 192)) * 8);
    // A: load z rows (coalesced), convert to bf16
    {
      float4 z0 = *(const float4*)(zrow + k0);
      float4 z1 = *(const float4*)(zrow + k0 + 4);
      short8 pk;
      pk[0] = (short)f2bf(z0.x); pk[1] = (short)f2bf(z0.y);
      pk[2] = (short)f2bf(z0.z); pk[3] = (short)f2bf(z0.w);
      pk[4] = (short)f2bf(z1.x); pk[5] = (short)f2bf(z1.y);
      pk[6] = (short)f2bf(z1.z); pk[7] = (short)f2bf(z1.w);
      *(short8*)&As[akq][am][0] = pk;
    }
    __syncthreads();
    bf16x8 afr[4], bfr[4];
#pragma unroll
    for (int mf = 0; mf < 4; ++mf) afr[mf] = *(const bf16x8*)&As[ql][mf * 16 + r16][0];
#pragma unroll
    for (int nf = 0; nf < 4; ++nf) bfr[nf] = *(const bf16x8*)&Bs[ql][wave * 64 + nf * 16 + r16][0];
#pragma unroll
    for (int mf = 0; mf < 4; ++mf)
#pragma unroll
      for (int nf = 0; nf < 4; ++nf)
        acc[mf][nf] = __builtin_amdgcn_mfma_f32_16x16x32_bf16(afr[mf], bfr[nf], acc[mf][nf], 0, 0, 0);
    __syncthreads();
  }

  const int n0 = n0b + wave * 64;
#pragma unroll
  for (int nf = 0; nf < 4; ++nf) {
    const int col = n0 + nf * 16 + r16;
#pragma unroll
    for (int mf = 0; mf < 4; ++mf)
#pragma unroll
      for (int p = 0; p < 4; ++p)
        zW[(size_t)(row0 + mf * 16 + ql * 4 + p) * DH + col] = f2bf(acc[mf][nf][p]);
  }
}

// ---------------------------------------------------------------------------
// kB: column stats of s = zW[a0]+zW[a1]+zW[a2] (b1 cancels in BN).
// grid: 1024 blocks (128 rows each), 256 thr. Wave rg reads whole 1KB zW rows
// coalesced (lane = col chunk); per-thread accumulation over 32 rows.
// ---------------------------------------------------------------------------
__global__ __launch_bounds__(256) void kB_stats(
    const unsigned short* __restrict__ zW, const int* __restrict__ tbl,
    float* __restrict__ psum, float* __restrict__ psq) {
  __shared__ int idxs[128][3];
  __shared__ float red1[4][512];
  __shared__ float red2[4][512];
  const int bid = blockIdx.x;
  const int blk = (bid & 7) * (NBS >> 3) + (bid >> 3);   // XCD-chunk swizzle (bijective)
  const int tid = threadIdx.x;
  const int row0 = blk * 128;
  const unsigned short* zWb = zW + (size_t)(row0 >> 11) * NA * DH;

  for (int i = tid; i < 384; i += 256) ((int*)idxs)[i] = tbl[(size_t)row0 * 3 + i];
  __syncthreads();

  const int cc = tid & 63, rg = tid >> 6;
  float s1[8] = {0, 0, 0, 0, 0, 0, 0, 0};
  float s2[8] = {0, 0, 0, 0, 0, 0, 0, 0};
#pragma unroll 4
  for (int i = 0; i < 32; ++i) {
    const int r = rg * 32 + i;
    const unsigned short* p0 = zWb + (size_t)idxs[r][0] * DH + cc * 8;
    const unsigned short* p1 = zWb + (size_t)idxs[r][1] * DH + cc * 8;
    const unsigned short* p2 = zWb + (size_t)idxs[r][2] * DH + cc * 8;
    short8 v0 = *(const short8*)p0;
    short8 v1 = *(const short8*)p1;
    short8 v2 = *(const short8*)p2;
#pragma unroll
    for (int j = 0; j < 8; ++j) {
      float h = bf2f((unsigned short)v0[j]) + bf2f((unsigned short)v1[j]) + bf2f((unsigned short)v2[j]);
      s1[j] += h;
      s2[j] = fmaf(h, h, s2[j]);
    }
  }
#pragma unroll
  for (int j = 0; j < 8; ++j) { red1[rg][cc * 8 + j] = s1[j]; red2[rg][cc * 8 + j] = s2[j]; }
  __syncthreads();
  for (int c = tid; c < 512; c += 256) {
    psum[(size_t)c * NBS + blk] = red1[0][c] + red1[1][c] + red1[2][c] + red1[3][c];
    psq [(size_t)c * NBS + blk] = red2[0][c] + red2[1][c] + red2[2][c] + red2[3][c];
  }
}

// ---------------------------------------------------------------------------
// k2: reduce partials -> a = gamma*rsqrt(var+eps), d = beta - mean*a
// ---------------------------------------------------------------------------
__global__ void k2_stats(const float* __restrict__ psum, const float* __restrict__ psq,
                         const float* __restrict__ gamma, const float* __restrict__ beta,
                         float* __restrict__ coef) {
  const int col = blockIdx.x, lane = threadIdx.x;
  float s1 = 0.f, s2 = 0.f;
  for (int i = lane; i < NBS; i += 64) {
    s1 += psum[(size_t)col * NBS + i];
    s2 += psq [(size_t)col * NBS + i];
  }
#pragma unroll
  for (int d = 1; d < 64; d <<= 1) { s1 += __shfl_xor(s1, d); s2 += __shfl_xor(s2, d); }
  if (lane == 0) {
    const float inv = 1.0f / (float)M;
    float mean = s1 * inv;
    float var  = s2 * inv - mean * mean;
    float a = gamma[col] * rsqrtf(var + 1e-5f);
    coef[col]      = a;
    coef[DH + col] = beta[col] - mean * a;
  }
}

// ---------------------------------------------------------------------------
// kC: out = relu((zW[a0]+zW[a1]+zW[a2])*a + d) @ W2 + b2
// grid: 2048 blocks (64 rows x 256 cols), 256 thr (4 waves); wave w: cols [w*64,+64)
// B staged via global_load_lds; A gathered from L2-resident zW with 1-step
// register prefetch under the MFMA section.
// ---------------------------------------------------------------------------
__global__ __launch_bounds__(256) void kC_out(
    const unsigned short* __restrict__ zW, const int* __restrict__ tbl,
    const unsigned short* __restrict__ W2T, const float* __restrict__ coef,
    const float* __restrict__ b2, float* __restrict__ out) {
  __shared__ __align__(16) unsigned short As[4][64][8];    // [kq][m][8]  4KB
  __shared__ __align__(16) unsigned short Bs[4][256][8];   // [kq][n][8] 16KB
  __shared__ float aC[DH], dC[DH], bC[DO];
  __shared__ int idxs[64][3];

  const int bid = blockIdx.x;
  const int blk = (bid & 7) * (NBC >> 3) + (bid >> 3);     // XCD-chunk swizzle (bijective)
  const int tid = threadIdx.x;
  const int row0 = blk * 64;
  const unsigned short* zWb = zW + (size_t)(row0 >> 11) * NA * DH;

  if (tid < 192) ((int*)idxs)[tid] = tbl[(size_t)row0 * 3 + tid];
  aC[tid]       = coef[tid];            aC[tid + 256] = coef[tid + 256];
  dC[tid]       = coef[DH + tid];       dC[tid + 256] = coef[DH + tid + 256];
  bC[tid]       = b2[tid];
  __syncthreads();

  const int wave = tid >> 6, lane = tid & 63, ql = lane >> 4, r16 = lane & 15;
  const int am = tid >> 2, akq = tid & 3;                  // 4 threads/row, 8 cols each

  const unsigned short* g0p = zWb + (size_t)idxs[am][0] * DH + akq * 8;
  const unsigned short* g1p = zWb + (size_t)idxs[am][1] * DH + akq * 8;
  const unsigned short* g2p = zWb + (size_t)idxs[am][2] * DH + akq * 8;
  short8 g0 = *(const short8*)g0p;
  short8 g1 = *(const short8*)g1p;
  short8 g2 = *(const short8*)g2p;

  f32x4 acc[4][4] = {};

  for (int s = 0; s < 16; ++s) {
    const int k0 = s * 32;
    // B: async stage W2T[0..256][k0..k0+32]
#pragma unroll
    for (int i = 0; i < 4; ++i)
      gl_lds16(W2T + (size_t)tid * DH + k0 + i * 8,
               (unsigned short*)Bs + (size_t)(i * 256 + (tid & 192)) * 8);
    // A: gathered sum (prefetched) -> affine -> relu -> bf16
    {
      f32x4 av0 = *(const f32x4*)&aC[k0 + akq * 8];
      f32x4 av1 = *(const f32x4*)&aC[k0 + akq * 8 + 4];
      f32x4 dv0 = *(const f32x4*)&dC[k0 + akq * 8];
      f32x4 dv1 = *(const f32x4*)&dC[k0 + akq * 8 + 4];
      short8 pk;
#pragma unroll
      for (int j = 0; j < 8; ++j) {
        float h = bf2f((unsigned short)g0[j]) + bf2f((unsigned short)g1[j]) + bf2f((unsigned short)g2[j]);
        float a = (j < 4) ? av0[j] : av1[j - 4];
        float d = (j < 4) ? dv0[j] : dv1[j - 4];
        float f = fmaf(h, a, d);
        f = f > 0.f ? f : 0.f;
        pk[j] = (short)f2bf(f);
      }
      *(short8*)&As[akq][am][0] = pk;
    }
    __syncthreads();                    // drains B-stage (vmcnt0) + As visible
    // prefetch next-step gathers; their latency hides under frag reads + MFMA
    if (s < 15) {
      g0 = *(const short8*)(g0p + k0 + 32);
      g1 = *(const short8*)(g1p + k0 + 32);
      g2 = *(const short8*)(g2p + k0 + 32);
    }
    bf16x8 afr[4], bfr[4];
#pragma unroll
    for (int mf = 0; mf < 4; ++mf) afr[mf] = *(const bf16x8*)&As[ql][mf * 16 + r16][0];
#pragma unroll
    for (int nf = 0; nf < 4; ++nf) bfr[nf] = *(const bf16x8*)&Bs[ql][wave * 64 + nf * 16 + r16][0];
#pragma unroll
    for (int mf = 0; mf < 4; ++mf)
#pragma unroll
      for (int nf = 0; nf < 4; ++nf)
        acc[mf][nf] = __builtin_amdgcn_mfma_f32_16x16x32_bf16(afr[mf], bfr[nf], acc[mf][nf], 0, 0, 0);
    __syncthreads();
  }

  const int n0 = wave * 64;
#pragma unroll
  for (int nf = 0; nf < 4; ++nf) {
    const int col = n0 + nf * 16 + r16;
    const float bv = bC[col];
#pragma unroll
    for (int mf = 0; mf < 4; ++mf)
#pragma unroll
      for (int p = 0; p < 4; ++p)
        out[(size_t)(row0 + mf * 16 + ql * 4 + p) * DO + col] = acc[mf][nf][p] + bv;
  }
}

// ---------------------------------------------------------------------------
// workspace layout (bytes):
//   [0,256K)      W1T bf16 [512][256]
//   [256K,512K)   W2T bf16 [256][512]
//   [512K,516K)   coef f32 [1024] (a then d)
//   [1M,3M)       psum f32 [512][1024]
//   [3M,5M)       psumsq f32 [512][1024]
//   [16M,32M)     zW bf16 [16384][512]
// ---------------------------------------------------------------------------
extern "C" void kernel_launch(void* const* d_in, const int* in_sizes, int n_in,
                              void* d_out, int out_size, void* d_ws, size_t ws_size,
                              hipStream_t stream) {
  const float* z     = (const float*)d_in[0];
  const int*   tbl   = (const int*)d_in[1];
  const float* W1    = (const float*)d_in[2];
  // d_in[3] = b1: unused — BatchNorm cancels a constant column shift exactly
  const float* gamma = (const float*)d_in[4];
  const float* beta  = (const float*)d_in[5];
  const float* W2    = (const float*)d_in[6];
  const float* b2    = (const float*)d_in[7];
  float* out = (float*)d_out;

  char* ws = (char*)d_ws;
  unsigned short* W1T  = (unsigned short*)(ws);
  unsigned short* W2T  = (unsigned short*)(ws + (256 << 10));
  float*          coef = (float*)(ws + (512 << 10));
  float*          psum = (float*)(ws + (1 << 20));
  float*          psq  = (float*)(ws + (3 << 20));
  unsigned short* zW   = (unsigned short*)(ws + (16 << 20));

  prep_kernel<<<512, 256, 0, stream>>>(W1, W2, W1T, W2T);
  kA_zw<<<512, 256, 0, stream>>>(z, W1T, zW);
  kB_stats<<<NBS, 256, 0, stream>>>(zW, tbl, psum, psq);
  k2_stats<<<DH, 64, 0, stream>>>(psum, psq, gamma, beta, coef);
  kC_out<<<NBC, 256, 0, stream>>>(zW, tbl, W2T, coef, b2, out);
}

// Round 2
// 272.136 us; speedup vs baseline: 1.7751x; 1.0393x over previous
//
#include <hip/hip_runtime.h>

// Problem constants
static constexpr int Bn  = 64;     // batch
static constexpr int T   = 2048;   // angles
static constexpr int NA  = 256;    // atoms
static constexpr int DA  = 256;    // d_atom (K1)
static constexpr int DH  = 512;    // d_hid  (N1 / K2)
static constexpr int DO  = 256;    // d_out  (N2)
static constexpr int M   = Bn * T;         // 131072 rows
static constexpr int NBS = M / 128;        // 1024 stat blocks
static constexpr int NBC = M / 64;         // 2048 output blocks

typedef __attribute__((ext_vector_type(4))) float  f32x4;
typedef __attribute__((ext_vector_type(8))) __bf16 bf16x8;
typedef __attribute__((ext_vector_type(8))) short  short8;

__device__ __forceinline__ unsigned short f2bf(float f) {
  union { float f; unsigned u; } v; v.f = f;
  unsigned u = v.u + 0x7FFFu + ((v.u >> 16) & 1u);   // RNE
  return (unsigned short)(u >> 16);
}
__device__ __forceinline__ float bf2f(unsigned short b) {
  union { unsigned u; float f; } v; v.u = ((unsigned)b) << 16;
  return v.f;
}

// async global->LDS, 16B per lane; lds ptr must be wave-uniform base
__device__ __forceinline__ void gl_lds16(const void* g, void* l) {
  __builtin_amdgcn_global_load_lds(
      (const __attribute__((address_space(1))) unsigned int*)g,
      (__attribute__((address_space(3))) unsigned int*)l, 16, 0, 0);
}

// ---------------------------------------------------------------------------
// prep: W1 [256x512] f32 -> W1T [512][256] bf16 ; W2 [512x256] f32 -> W2T [256][512] bf16
// ---------------------------------------------------------------------------
__global__ void prep_kernel(const float* __restrict__ W1, const float* __restrict__ W2,
                            unsigned short* __restrict__ W1T, unsigned short* __restrict__ W2T) {
  int id = blockIdx.x * 256 + threadIdx.x;           // 131072 threads
  {
    int n = id >> 8, k = id & 255;                   // W1T[n][k] = W1[k][n]
    W1T[id] = f2bf(W1[k * DH + n]);
  }
  {
    int n = id >> 9, k = id & 511;                   // W2T[n][k] = W2[k][n]
    W2T[id] = f2bf(W2[k * DO + n]);
  }
}

// ---------------------------------------------------------------------------
// kA: zW = bf16(z @ W1).  16384 x 512, K=256.
// grid: 512 blocks = 256 m-tiles x 2 n-halves, 256 threads (4 waves).
// Phase-split: produce full A tile [64][256] once, then 8 barrier-free MFMA
// steps with wave-local double-buffered B staging (counted vmcnt).
// ---------------------------------------------------------------------------
__global__ __launch_bounds__(256) void kA_zw(
    const float* __restrict__ z, const unsigned short* __restrict__ W1T,
    unsigned short* __restrict__ zW) {
  __shared__ __align__(16) unsigned short As[32][64][8];      // [g][row][8] 32KB
  __shared__ __align__(16) unsigned short Bs[2][4][256][8];   // dbuf 32KB
  const int tid = threadIdx.x;
  const int bm = blockIdx.x >> 1, bn = blockIdx.x & 1;
  const int row0 = bm * 64, n0b = bn * 256;
  const int wave = tid >> 6, lane = tid & 63, ql = lane >> 4, r16 = lane & 15;
  const int gr = tid >> 2, sub = tid & 3;
  const int sxw = (sub << 2) ^ sub;                  // 0,5,10,15 store swizzle
  const int sxr = (ql << 2) ^ ql;                    // matching read swizzle

  auto stageB = [&](int buf, int k0) {
#pragma unroll
    for (int i = 0; i < 4; ++i)
      gl_lds16(W1T + (size_t)(n0b + tid) * DA + k0 + i * 8,
               (unsigned short*)Bs + (size_t)((buf * 4 + i) * 256 + wave * 64) * 8);
  };

  stageB(0, 0);                                      // prologue stage for s=0

  // ---- produce full A tile: z rows f32 -> bf16, swizzled rows ----
  {
    const float* zr = z + (size_t)(row0 + gr) * DA + sub * 8;
    f32x4 za[16];
#pragma unroll
    for (int c = 0; c < 8; ++c) {
      za[2 * c]     = *(const f32x4*)(zr + c * 32);
      za[2 * c + 1] = *(const f32x4*)(zr + c * 32 + 4);
    }
#pragma unroll
    for (int c = 0; c < 8; ++c) {
      bf16x8 pk;
#pragma unroll
      for (int j = 0; j < 4; ++j) {
        pk[j]     = (__bf16)za[2 * c][j];
        pk[4 + j] = (__bf16)za[2 * c + 1][j];
      }
      *(bf16x8*)&As[c * 4 + sub][gr ^ sxw][0] = pk;
    }
  }
  asm volatile("s_waitcnt lgkmcnt(0)" ::: "memory"); // A stores visible
  __builtin_amdgcn_s_barrier();                      // (keeps stage loads in flight)

  f32x4 acc[4][4] = {};
  for (int s = 0; s < 8; ++s) {
    asm volatile("s_waitcnt lgkmcnt(0)" ::: "memory");   // WAR: prev-step B reads done
    if (s < 7) {
      stageB((s + 1) & 1, (s + 1) * 32);
      asm volatile("s_waitcnt vmcnt(4)" ::: "memory");   // cur buffer complete
    } else {
      asm volatile("s_waitcnt vmcnt(0)" ::: "memory");
    }
    bf16x8 afr[4], bfr[4];
#pragma unroll
    for (int mf = 0; mf < 4; ++mf)
      afr[mf] = *(const bf16x8*)&As[s * 4 + ql][(mf * 16 + r16) ^ sxr][0];
#pragma unroll
    for (int nf = 0; nf < 4; ++nf)
      bfr[nf] = *(const bf16x8*)&Bs[s & 1][ql][wave * 64 + nf * 16 + r16][0];
    __builtin_amdgcn_s_setprio(1);
#pragma unroll
    for (int mf = 0; mf < 4; ++mf)
#pragma unroll
      for (int nf = 0; nf < 4; ++nf)
        acc[mf][nf] = __builtin_amdgcn_mfma_f32_16x16x32_bf16(afr[mf], bfr[nf], acc[mf][nf], 0, 0, 0);
    __builtin_amdgcn_s_setprio(0);
  }

  const int n0 = n0b + wave * 64;
#pragma unroll
  for (int nf = 0; nf < 4; ++nf) {
    const int col = n0 + nf * 16 + r16;
#pragma unroll
    for (int mf = 0; mf < 4; ++mf)
#pragma unroll
      for (int p = 0; p < 4; ++p)
        zW[(size_t)(row0 + mf * 16 + ql * 4 + p) * DH + col] = f2bf(acc[mf][nf][p]);
  }
}

// ---------------------------------------------------------------------------
// kB: column stats of s = zW[a0]+zW[a1]+zW[a2] (b1 cancels in BN).
// ---------------------------------------------------------------------------
__global__ __launch_bounds__(256) void kB_stats(
    const unsigned short* __restrict__ zW, const int* __restrict__ tbl,
    float* __restrict__ psum, float* __restrict__ psq) {
  __shared__ int idxs[128][3];
  __shared__ float red1[4][512];
  __shared__ float red2[4][512];
  const int bid = blockIdx.x;
  const int blk = (bid & 7) * (NBS >> 3) + (bid >> 3);   // XCD-chunk swizzle (bijective)
  const int tid = threadIdx.x;
  const int row0 = blk * 128;
  const unsigned short* zWb = zW + (size_t)(row0 >> 11) * NA * DH;

  for (int i = tid; i < 384; i += 256) ((int*)idxs)[i] = tbl[(size_t)row0 * 3 + i];
  __syncthreads();

  const int cc = tid & 63, rg = tid >> 6;
  float s1[8] = {0, 0, 0, 0, 0, 0, 0, 0};
  float s2[8] = {0, 0, 0, 0, 0, 0, 0, 0};
#pragma unroll 8
  for (int i = 0; i < 32; ++i) {
    const int r = rg * 32 + i;
    const unsigned short* p0 = zWb + (size_t)idxs[r][0] * DH + cc * 8;
    const unsigned short* p1 = zWb + (size_t)idxs[r][1] * DH + cc * 8;
    const unsigned short* p2 = zWb + (size_t)idxs[r][2] * DH + cc * 8;
    short8 v0 = *(const short8*)p0;
    short8 v1 = *(const short8*)p1;
    short8 v2 = *(const short8*)p2;
#pragma unroll
    for (int j = 0; j < 8; ++j) {
      float h = bf2f((unsigned short)v0[j]) + bf2f((unsigned short)v1[j]) + bf2f((unsigned short)v2[j]);
      s1[j] += h;
      s2[j] = fmaf(h, h, s2[j]);
    }
  }
#pragma unroll
  for (int j = 0; j < 8; ++j) { red1[rg][cc * 8 + j] = s1[j]; red2[rg][cc * 8 + j] = s2[j]; }
  __syncthreads();
  for (int c = tid; c < 512; c += 256) {
    psum[(size_t)c * NBS + blk] = red1[0][c] + red1[1][c] + red1[2][c] + red1[3][c];
    psq [(size_t)c * NBS + blk] = red2[0][c] + red2[1][c] + red2[2][c] + red2[3][c];
  }
}

// ---------------------------------------------------------------------------
// k2: reduce partials -> a = gamma*rsqrt(var+eps), d = beta - mean*a
// ---------------------------------------------------------------------------
__global__ void k2_stats(const float* __restrict__ psum, const float* __restrict__ psq,
                         const float* __restrict__ gamma, const float* __restrict__ beta,
                         float* __restrict__ coef) {
  const int col = blockIdx.x, lane = threadIdx.x;
  float s1 = 0.f, s2 = 0.f;
  for (int i = lane; i < NBS; i += 64) {
    s1 += psum[(size_t)col * NBS + i];
    s2 += psq [(size_t)col * NBS + i];
  }
#pragma unroll
  for (int d = 1; d < 64; d <<= 1) { s1 += __shfl_xor(s1, d); s2 += __shfl_xor(s2, d); }
  if (lane == 0) {
    const float inv = 1.0f / (float)M;
    float mean = s1 * inv;
    float var  = s2 * inv - mean * mean;
    float a = gamma[col] * rsqrtf(var + 1e-5f);
    coef[col]      = a;
    coef[DH + col] = beta[col] - mean * a;
  }
}

// ---------------------------------------------------------------------------
// kC: out = relu((zW[a0]+zW[a1]+zW[a2])*a + d) @ W2 + b2
// Phase-split: per K-half (256), produce A tile [64][256] once (gathers issued
// with full MLP), then 8 barrier-free MFMA steps; B wave-local dbuf, vmcnt(4).
// ---------------------------------------------------------------------------
__global__ __launch_bounds__(256) void kC_out(
    const unsigned short* __restrict__ zW, const int* __restrict__ tbl,
    const unsigned short* __restrict__ W2T, const float* __restrict__ coef,
    const float* __restrict__ b2, float* __restrict__ out) {
  __shared__ __align__(16) unsigned short As[32][64][8];      // [g][row][8] 32KB
  __shared__ __align__(16) unsigned short Bs[2][4][256][8];   // dbuf 32KB
  __shared__ float aC[DH], dC[DH], bC[DO];
  __shared__ int idxs[64][3];

  const int bid = blockIdx.x;
  const int blk = (bid & 7) * (NBC >> 3) + (bid >> 3);     // XCD-chunk swizzle (bijective)
  const int tid = threadIdx.x;
  const int row0 = blk * 64;
  const unsigned short* zWb = zW + (size_t)(row0 >> 11) * NA * DH;

  if (tid < 192) ((int*)idxs)[tid] = tbl[(size_t)row0 * 3 + tid];
  aC[tid]       = coef[tid];            aC[tid + 256] = coef[tid + 256];
  dC[tid]       = coef[DH + tid];       dC[tid + 256] = coef[DH + tid + 256];
  bC[tid]       = b2[tid];
  __syncthreads();

  const int wave = tid >> 6, lane = tid & 63, ql = lane >> 4, r16 = lane & 15;
  const int gr = tid >> 2, sub = tid & 3;
  const int sxw = (sub << 2) ^ sub;
  const int sxr = (ql << 2) ^ ql;

  const unsigned short* g0p = zWb + (size_t)idxs[gr][0] * DH + sub * 8;
  const unsigned short* g1p = zWb + (size_t)idxs[gr][1] * DH + sub * 8;
  const unsigned short* g2p = zWb + (size_t)idxs[gr][2] * DH + sub * 8;

  auto stageB = [&](int buf, int k0) {
#pragma unroll
    for (int i = 0; i < 4; ++i)
      gl_lds16(W2T + (size_t)tid * DH + k0 + i * 8,
               (unsigned short*)Bs + (size_t)((buf * 4 + i) * 256 + wave * 64) * 8);
  };

  stageB(0, 0);                                      // prologue stage for sg=0

  f32x4 acc[4][4] = {};

  for (int h = 0; h < 2; ++h) {
    const int kh = h * 256;
    // ---- issue all gathers for this half (24 L2 loads, full MLP) ----
    short8 v0[8], v1[8], v2[8];
#pragma unroll
    for (int c = 0; c < 8; ++c) {
      v0[c] = *(const short8*)(g0p + kh + c * 32);
      v1[c] = *(const short8*)(g1p + kh + c * 32);
      v2[c] = *(const short8*)(g2p + kh + c * 32);
    }
    if (h) {                                         // prev-half A reads done
      asm volatile("s_waitcnt lgkmcnt(0)" ::: "memory");
      __builtin_amdgcn_s_barrier();
    }
    // ---- sum + affine + relu -> bf16 A tile ----
#pragma unroll
    for (int c = 0; c < 8; ++c) {
      const int kk = kh + c * 32 + sub * 8;
      f32x4 av0 = *(const f32x4*)&aC[kk];
      f32x4 av1 = *(const f32x4*)&aC[kk + 4];
      f32x4 dv0 = *(const f32x4*)&dC[kk];
      f32x4 dv1 = *(const f32x4*)&dC[kk + 4];
      bf16x8 pk;
#pragma unroll
      for (int j = 0; j < 4; ++j) {
        float h0 = bf2f((unsigned short)v0[c][j]) + bf2f((unsigned short)v1[c][j]) + bf2f((unsigned short)v2[c][j]);
        float f0 = fmaf(h0, av0[j], dv0[j]);
        f0 = f0 > 0.f ? f0 : 0.f;
        pk[j] = (__bf16)f0;
        float h1 = bf2f((unsigned short)v0[c][4 + j]) + bf2f((unsigned short)v1[c][4 + j]) + bf2f((unsigned short)v2[c][4 + j]);
        float f1 = fmaf(h1, av1[j], dv1[j]);
        f1 = f1 > 0.f ? f1 : 0.f;
        pk[4 + j] = (__bf16)f1;
      }
      *(bf16x8*)&As[c * 4 + sub][gr ^ sxw][0] = pk;
    }
    asm volatile("s_waitcnt lgkmcnt(0)" ::: "memory"); // A stores visible
    __builtin_amdgcn_s_barrier();

    // ---- 8 barrier-free MFMA steps ----
    for (int s = 0; s < 8; ++s) {
      const int sg = h * 8 + s;
      asm volatile("s_waitcnt lgkmcnt(0)" ::: "memory"); // WAR: prev B reads done
      if (sg < 15) {
        stageB((sg + 1) & 1, (sg + 1) * 32);
        asm volatile("s_waitcnt vmcnt(4)" ::: "memory"); // cur buffer complete
      } else {
        asm volatile("s_waitcnt vmcnt(0)" ::: "memory");
      }
      bf16x8 afr[4], bfr[4];
#pragma unroll
      for (int mf = 0; mf < 4; ++mf)
        afr[mf] = *(const bf16x8*)&As[s * 4 + ql][(mf * 16 + r16) ^ sxr][0];
#pragma unroll
      for (int nf = 0; nf < 4; ++nf)
        bfr[nf] = *(const bf16x8*)&Bs[sg & 1][ql][wave * 64 + nf * 16 + r16][0];
      __builtin_amdgcn_s_setprio(1);
#pragma unroll
      for (int mf = 0; mf < 4; ++mf)
#pragma unroll
        for (int nf = 0; nf < 4; ++nf)
          acc[mf][nf] = __builtin_amdgcn_mfma_f32_16x16x32_bf16(afr[mf], bfr[nf], acc[mf][nf], 0, 0, 0);
      __builtin_amdgcn_s_setprio(0);
    }
  }

  const int n0 = wave * 64;
#pragma unroll
  for (int nf = 0; nf < 4; ++nf) {
    const int col = n0 + nf * 16 + r16;
    const float bv = bC[col];
#pragma unroll
    for (int mf = 0; mf < 4; ++mf)
#pragma unroll
      for (int p = 0; p < 4; ++p)
        out[(size_t)(row0 + mf * 16 + ql * 4 + p) * DO + col] = acc[mf][nf][p] + bv;
  }
}

// ---------------------------------------------------------------------------
// workspace layout (bytes):
//   [0,256K)      W1T bf16 [512][256]
//   [256K,512K)   W2T bf16 [256][512]
//   [512K,516K)   coef f32 [1024] (a then d)
//   [1M,3M)       psum f32 [512][1024]
//   [3M,5M)       psumsq f32 [512][1024]
//   [16M,32M)     zW bf16 [16384][512]
// ---------------------------------------------------------------------------
extern "C" void kernel_launch(void* const* d_in, const int* in_sizes, int n_in,
                              void* d_out, int out_size, void* d_ws, size_t ws_size,
                              hipStream_t stream) {
  const float* z     = (const float*)d_in[0];
  const int*   tbl   = (const int*)d_in[1];
  const float* W1    = (const float*)d_in[2];
  // d_in[3] = b1: unused — BatchNorm cancels a constant column shift exactly
  const float* gamma = (const float*)d_in[4];
  const float* beta  = (const float*)d_in[5];
  const float* W2    = (const float*)d_in[6];
  const float* b2    = (const float*)d_in[7];
  float* out = (float*)d_out;

  char* ws = (char*)d_ws;
  unsigned short* W1T  = (unsigned short*)(ws);
  unsigned short* W2T  = (unsigned short*)(ws + (256 << 10));
  float*          coef = (float*)(ws + (512 << 10));
  float*          psum = (float*)(ws + (1 << 20));
  float*          psq  = (float*)(ws + (3 << 20));
  unsigned short* zW   = (unsigned short*)(ws + (16 << 20));

  prep_kernel<<<512, 256, 0, stream>>>(W1, W2, W1T, W2T);
  kA_zw<<<512, 256, 0, stream>>>(z, W1T, zW);
  kB_stats<<<NBS, 256, 0, stream>>>(zW, tbl, psum, psq);
  k2_stats<<<DH, 64, 0, stream>>>(psum, psq, gamma, beta, coef);
  kC_out<<<NBC, 256, 0, stream>>>(zW, tbl, W2T, coef, b2, out);
}

// Round 3
// 268.761 us; speedup vs baseline: 1.7974x; 1.0126x over previous
//
#include <hip/hip_runtime.h>

// Problem constants
static constexpr int Bn  = 64;     // batch
static constexpr int T   = 2048;   // angles
static constexpr int NA  = 256;    // atoms
static constexpr int DA  = 256;    // d_atom (K1)
static constexpr int DH  = 512;    // d_hid  (N1 / K2)
static constexpr int DO  = 256;    // d_out  (N2)
static constexpr int M   = Bn * T;         // 131072 rows
static constexpr int NBS = M / 64;         // 2048 stat blocks
static constexpr int NBC = M / 64;         // 2048 output blocks

typedef __attribute__((ext_vector_type(4))) float  f32x4;
typedef __attribute__((ext_vector_type(8))) __bf16 bf16x8;
typedef __attribute__((ext_vector_type(8))) short  short8;

__device__ __forceinline__ unsigned short f2bf(float f) {
  union { float f; unsigned u; } v; v.f = f;
  unsigned u = v.u + 0x7FFFu + ((v.u >> 16) & 1u);   // RNE
  return (unsigned short)(u >> 16);
}
__device__ __forceinline__ float bf2f(unsigned short b) {
  union { unsigned u; float f; } v; v.u = ((unsigned)b) << 16;
  return v.f;
}

// ---------------------------------------------------------------------------
// prep: W1 [256x512] f32 -> W1T [512][256] bf16 ; W2 [512x256] f32 -> W2T [256][512] bf16
// ---------------------------------------------------------------------------
__global__ void prep_kernel(const float* __restrict__ W1, const float* __restrict__ W2,
                            unsigned short* __restrict__ W1T, unsigned short* __restrict__ W2T) {
  int id = blockIdx.x * 256 + threadIdx.x;           // 131072 threads
  {
    int n = id >> 8, k = id & 255;                   // W1T[n][k] = W1[k][n]
    W1T[id] = f2bf(W1[k * DH + n]);
  }
  {
    int n = id >> 9, k = id & 511;                   // W2T[n][k] = W2[k][n]
    W2T[id] = f2bf(W2[k * DO + n]);
  }
}

// ---------------------------------------------------------------------------
// kA: zW = bf16(z @ W1).  16384 x 512, K=256.
// grid: 512 blocks; XCD-aligned mapping: XCD x produces batches 8x..8x+7 so
// kB/kC (same chunk swizzle) read zW from their local L2.
// B fragments are per-lane contiguous 16B in W1T -> register double-buffer,
// no B LDS, no barriers in the MFMA loop.
// ---------------------------------------------------------------------------
__global__ __launch_bounds__(256) void kA_zw(
    const float* __restrict__ z, const unsigned short* __restrict__ W1T,
    unsigned short* __restrict__ zW) {
  __shared__ __align__(16) unsigned short As[32][64][8];      // [g][row][8] 32KB
  const int tid = threadIdx.x;
  const int xcd = blockIdx.x & 7, idx = blockIdx.x >> 3;
  const int bm = xcd * 32 + (idx >> 1), bn = idx & 1;         // batches 8x..8x+7 on XCD x
  const int row0 = bm * 64, n0b = bn * 256;
  const int wave = tid >> 6, lane = tid & 63, ql = lane >> 4, r16 = lane & 15;
  const int gr = tid >> 2, sub = tid & 3;
  const int sxw = (sub << 2) ^ sub;                  // store swizzle
  const int sxr = (ql << 2) ^ ql;                    // matching read swizzle

  // per-lane B pointer: frag(nf, s) = 16B at bp + nf*16*DA + s*32
  const unsigned short* bp = W1T + (size_t)(n0b + wave * 64 + r16) * DA + ql * 8;

  bf16x8 bq[2][4];
#pragma unroll
  for (int p = 0; p < 2; ++p)
#pragma unroll
    for (int nf = 0; nf < 4; ++nf)
      bq[p][nf] = *(const bf16x8*)(bp + nf * 16 * DA + p * 32);

  // ---- produce full A tile: z rows f32 -> bf16, swizzled rows ----
  {
    const float* zr = z + (size_t)(row0 + gr) * DA + sub * 8;
#pragma unroll
    for (int c = 0; c < 8; ++c) {
      f32x4 a0 = *(const f32x4*)(zr + c * 32);
      f32x4 a1 = *(const f32x4*)(zr + c * 32 + 4);
      bf16x8 pk;
#pragma unroll
      for (int j = 0; j < 4; ++j) { pk[j] = (__bf16)a0[j]; pk[4 + j] = (__bf16)a1[j]; }
      *(bf16x8*)&As[c * 4 + sub][gr ^ sxw][0] = pk;
    }
  }
  __syncthreads();

  f32x4 acc[4][4] = {};
#pragma unroll
  for (int s = 0; s < 8; ++s) {
    bf16x8 afr[4], bfr[4];
#pragma unroll
    for (int mf = 0; mf < 4; ++mf)
      afr[mf] = *(const bf16x8*)&As[s * 4 + ql][(mf * 16 + r16) ^ sxr][0];
#pragma unroll
    for (int nf = 0; nf < 4; ++nf) bfr[nf] = bq[s & 1][nf];
    __builtin_amdgcn_s_setprio(1);
#pragma unroll
    for (int mf = 0; mf < 4; ++mf)
#pragma unroll
      for (int nf = 0; nf < 4; ++nf)
        acc[mf][nf] = __builtin_amdgcn_mfma_f32_16x16x32_bf16(afr[mf], bfr[nf], acc[mf][nf], 0, 0, 0);
    __builtin_amdgcn_s_setprio(0);
    if (s + 2 < 8) {
#pragma unroll
      for (int nf = 0; nf < 4; ++nf)
        bq[s & 1][nf] = *(const bf16x8*)(bp + nf * 16 * DA + (s + 2) * 32);
    }
  }

  const int n0 = n0b + wave * 64;
#pragma unroll
  for (int nf = 0; nf < 4; ++nf) {
    const int col = n0 + nf * 16 + r16;
#pragma unroll
    for (int mf = 0; mf < 4; ++mf)
#pragma unroll
      for (int p = 0; p < 4; ++p)
        zW[(size_t)(row0 + mf * 16 + ql * 4 + p) * DH + col] = f2bf(acc[mf][nf][p]);
  }
}

// ---------------------------------------------------------------------------
// kB: column stats of s = zW[a0]+zW[a1]+zW[a2] (b1 cancels in BN).
// 2048 blocks x 64 rows; chunk swizzle matches kA's producer XCD.
// ---------------------------------------------------------------------------
__global__ __launch_bounds__(256) void kB_stats(
    const unsigned short* __restrict__ zW, const int* __restrict__ tbl,
    float* __restrict__ psum, float* __restrict__ psq) {
  __shared__ int idxs[64][3];
  __shared__ float red1[4][512];
  __shared__ float red2[4][512];
  const int bid = blockIdx.x;
  const int blk = (bid & 7) * (NBS >> 3) + (bid >> 3);   // XCD-chunk swizzle (bijective)
  const int tid = threadIdx.x;
  const int row0 = blk * 64;
  const unsigned short* zWb = zW + (size_t)(row0 >> 11) * NA * DH;

  if (tid < 192) ((int*)idxs)[tid] = tbl[(size_t)row0 * 3 + tid];
  __syncthreads();

  const int cc = tid & 63, rg = tid >> 6;
  float s1[8] = {0, 0, 0, 0, 0, 0, 0, 0};
  float s2[8] = {0, 0, 0, 0, 0, 0, 0, 0};
#pragma unroll 8
  for (int i = 0; i < 16; ++i) {
    const int r = rg * 16 + i;
    const unsigned short* p0 = zWb + (size_t)idxs[r][0] * DH + cc * 8;
    const unsigned short* p1 = zWb + (size_t)idxs[r][1] * DH + cc * 8;
    const unsigned short* p2 = zWb + (size_t)idxs[r][2] * DH + cc * 8;
    short8 v0 = *(const short8*)p0;
    short8 v1 = *(const short8*)p1;
    short8 v2 = *(const short8*)p2;
#pragma unroll
    for (int j = 0; j < 8; ++j) {
      float h = bf2f((unsigned short)v0[j]) + bf2f((unsigned short)v1[j]) + bf2f((unsigned short)v2[j]);
      s1[j] += h;
      s2[j] = fmaf(h, h, s2[j]);
    }
  }
#pragma unroll
  for (int j = 0; j < 8; ++j) { red1[rg][cc * 8 + j] = s1[j]; red2[rg][cc * 8 + j] = s2[j]; }
  __syncthreads();
  for (int c = tid; c < 512; c += 256) {
    psum[(size_t)c * NBS + blk] = red1[0][c] + red1[1][c] + red1[2][c] + red1[3][c];
    psq [(size_t)c * NBS + blk] = red2[0][c] + red2[1][c] + red2[2][c] + red2[3][c];
  }
}

// ---------------------------------------------------------------------------
// k2: reduce partials -> a = gamma*rsqrt(var+eps), d = beta - mean*a
// ---------------------------------------------------------------------------
__global__ void k2_stats(const float* __restrict__ psum, const float* __restrict__ psq,
                         const float* __restrict__ gamma, const float* __restrict__ beta,
                         float* __restrict__ coef) {
  const int col = blockIdx.x, lane = threadIdx.x;
  float s1 = 0.f, s2 = 0.f;
  for (int i = lane; i < NBS; i += 64) {
    s1 += psum[(size_t)col * NBS + i];
    s2 += psq [(size_t)col * NBS + i];
  }
#pragma unroll
  for (int d = 1; d < 64; d <<= 1) { s1 += __shfl_xor(s1, d); s2 += __shfl_xor(s2, d); }
  if (lane == 0) {
    const float inv = 1.0f / (float)M;
    float mean = s1 * inv;
    float var  = s2 * inv - mean * mean;
    float a = gamma[col] * rsqrtf(var + 1e-5f);
    coef[col]      = a;
    coef[DH + col] = beta[col] - mean * a;
  }
}

// ---------------------------------------------------------------------------
// kC: out = relu((zW[a0]+zW[a1]+zW[a2])*a + d) @ W2 + b2
// B in registers (2-deep queue, per-lane contiguous 16B frags of W2T);
// A per K-half in LDS (32KB single buffer); 3 barriers per block total.
// ---------------------------------------------------------------------------
__global__ __launch_bounds__(256, 3) void kC_out(
    const unsigned short* __restrict__ zW, const int* __restrict__ tbl,
    const unsigned short* __restrict__ W2T, const float* __restrict__ coef,
    const float* __restrict__ b2, float* __restrict__ out) {
  __shared__ __align__(16) unsigned short As[32][64][8];      // [g][row][8] 32KB
  __shared__ float aC[DH], dC[DH];
  __shared__ int idxs[64][3];

  const int bid = blockIdx.x;
  const int blk = (bid & 7) * (NBC >> 3) + (bid >> 3);     // XCD-chunk swizzle (bijective)
  const int tid = threadIdx.x;
  const int row0 = blk * 64;
  const unsigned short* zWb = zW + (size_t)(row0 >> 11) * NA * DH;

  if (tid < 192) ((int*)idxs)[tid] = tbl[(size_t)row0 * 3 + tid];
  aC[tid]       = coef[tid];            aC[tid + 256] = coef[tid + 256];
  dC[tid]       = coef[DH + tid];       dC[tid + 256] = coef[DH + tid + 256];
  __syncthreads();

  const int wave = tid >> 6, lane = tid & 63, ql = lane >> 4, r16 = lane & 15;
  const int gr = tid >> 2, sub = tid & 3;
  const int sxw = (sub << 2) ^ sub;
  const int sxr = (ql << 2) ^ ql;

  const unsigned short* g0p = zWb + (size_t)idxs[gr][0] * DH + sub * 8;
  const unsigned short* g1p = zWb + (size_t)idxs[gr][1] * DH + sub * 8;
  const unsigned short* g2p = zWb + (size_t)idxs[gr][2] * DH + sub * 8;

  // per-lane B pointer: frag(nf, sg) = 16B at bp + nf*16*DH + sg*32
  const unsigned short* bp = W2T + (size_t)(wave * 64 + r16) * DH + ql * 8;

  bf16x8 bq[2][4];
#pragma unroll
  for (int p = 0; p < 2; ++p)
#pragma unroll
    for (int nf = 0; nf < 4; ++nf)
      bq[p][nf] = *(const bf16x8*)(bp + nf * 16 * DH + p * 32);

  f32x4 acc[4][4] = {};

#pragma unroll
  for (int h = 0; h < 2; ++h) {
    const int kh = h * 256;
    if (h) __builtin_amdgcn_s_barrier();             // WAR: all As reads of half 0 done
    // ---- A-phase: gather + affine + relu -> bf16 As tile (per-c pipeline) ----
#pragma unroll
    for (int c = 0; c < 8; ++c) {
      short8 v0 = *(const short8*)(g0p + kh + c * 32);
      short8 v1 = *(const short8*)(g1p + kh + c * 32);
      short8 v2 = *(const short8*)(g2p + kh + c * 32);
      const int kk = kh + c * 32 + sub * 8;
      f32x4 av0 = *(const f32x4*)&aC[kk];
      f32x4 av1 = *(const f32x4*)&aC[kk + 4];
      f32x4 dv0 = *(const f32x4*)&dC[kk];
      f32x4 dv1 = *(const f32x4*)&dC[kk + 4];
      bf16x8 pk;
#pragma unroll
      for (int j = 0; j < 4; ++j) {
        float h0 = bf2f((unsigned short)v0[j]) + bf2f((unsigned short)v1[j]) + bf2f((unsigned short)v2[j]);
        float f0 = fmaf(h0, av0[j], dv0[j]);
        f0 = f0 > 0.f ? f0 : 0.f;
        pk[j] = (__bf16)f0;
        float h1 = bf2f((unsigned short)v0[4 + j]) + bf2f((unsigned short)v1[4 + j]) + bf2f((unsigned short)v2[4 + j]);
        float f1 = fmaf(h1, av1[j], dv1[j]);
        f1 = f1 > 0.f ? f1 : 0.f;
        pk[4 + j] = (__bf16)f1;
      }
      *(bf16x8*)&As[c * 4 + sub][gr ^ sxw][0] = pk;
    }
    asm volatile("s_waitcnt lgkmcnt(0)" ::: "memory"); // A stores visible
    __builtin_amdgcn_s_barrier();
    __builtin_amdgcn_sched_barrier(0);                 // no read hoisting above barrier

    // ---- 8 barrier-free MFMA steps; B from register queue ----
#pragma unroll
    for (int s = 0; s < 8; ++s) {
      const int sg = h * 8 + s;
      bf16x8 afr[4], bfr[4];
#pragma unroll
      for (int mf = 0; mf < 4; ++mf)
        afr[mf] = *(const bf16x8*)&As[s * 4 + ql][(mf * 16 + r16) ^ sxr][0];
#pragma unroll
      for (int nf = 0; nf < 4; ++nf) bfr[nf] = bq[sg & 1][nf];
      __builtin_amdgcn_s_setprio(1);
#pragma unroll
      for (int mf = 0; mf < 4; ++mf)
#pragma unroll
        for (int nf = 0; nf < 4; ++nf)
          acc[mf][nf] = __builtin_amdgcn_mfma_f32_16x16x32_bf16(afr[mf], bfr[nf], acc[mf][nf], 0, 0, 0);
      __builtin_amdgcn_s_setprio(0);
      if (sg + 2 < 16) {
#pragma unroll
        for (int nf = 0; nf < 4; ++nf)
          bq[sg & 1][nf] = *(const bf16x8*)(bp + nf * 16 * DH + (sg + 2) * 32);
      }
    }
  }

  const int n0 = wave * 64;
#pragma unroll
  for (int nf = 0; nf < 4; ++nf) {
    const int col = n0 + nf * 16 + r16;
    const float bv = b2[col];
#pragma unroll
    for (int mf = 0; mf < 4; ++mf)
#pragma unroll
      for (int p = 0; p < 4; ++p)
        out[(size_t)(row0 + mf * 16 + ql * 4 + p) * DO + col] = acc[mf][nf][p] + bv;
  }
}

// ---------------------------------------------------------------------------
// workspace layout (bytes):
//   [0,256K)      W1T bf16 [512][256]
//   [256K,512K)   W2T bf16 [256][512]
//   [512K,516K)   coef f32 [1024] (a then d)
//   [2M,6M)       psum f32 [512][2048]
//   [6M,10M)      psumsq f32 [512][2048]
//   [16M,32M)     zW bf16 [16384][512]
// ---------------------------------------------------------------------------
extern "C" void kernel_launch(void* const* d_in, const int* in_sizes, int n_in,
                              void* d_out, int out_size, void* d_ws, size_t ws_size,
                              hipStream_t stream) {
  const float* z     = (const float*)d_in[0];
  const int*   tbl   = (const int*)d_in[1];
  const float* W1    = (const float*)d_in[2];
  // d_in[3] = b1: unused — BatchNorm cancels a constant column shift exactly
  const float* gamma = (const float*)d_in[4];
  const float* beta  = (const float*)d_in[5];
  const float* W2    = (const float*)d_in[6];
  const float* b2    = (const float*)d_in[7];
  float* out = (float*)d_out;

  char* ws = (char*)d_ws;
  unsigned short* W1T  = (unsigned short*)(ws);
  unsigned short* W2T  = (unsigned short*)(ws + (256 << 10));
  float*          coef = (float*)(ws + (512 << 10));
  float*          psum = (float*)(ws + (2 << 20));
  float*          psq  = (float*)(ws + (6 << 20));
  unsigned short* zW   = (unsigned short*)(ws + (16 << 20));

  prep_kernel<<<512, 256, 0, stream>>>(W1, W2, W1T, W2T);
  kA_zw<<<512, 256, 0, stream>>>(z, W1T, zW);
  kB_stats<<<NBS, 256, 0, stream>>>(zW, tbl, psum, psq);
  k2_stats<<<DH, 64, 0, stream>>>(psum, psq, gamma, beta, coef);
  kC_out<<<NBC, 256, 0, stream>>>(zW, tbl, W2T, coef, b2, out);
}

// Round 4
// 268.476 us; speedup vs baseline: 1.7993x; 1.0011x over previous
//
#include <hip/hip_runtime.h>

// Problem constants
static constexpr int Bn  = 64;     // batch
static constexpr int T   = 2048;   // angles
static constexpr int NA  = 256;    // atoms
static constexpr int DA  = 256;    // d_atom (K1)
static constexpr int DH  = 512;    // d_hid  (N1 / K2)
static constexpr int DO  = 256;    // d_out  (N2)
static constexpr int M   = Bn * T;         // 131072 rows
static constexpr int NBS = M / 128;        // 1024 stat blocks
static constexpr int NBC = M / 64;         // 2048 output blocks

typedef __attribute__((ext_vector_type(4))) float  f32x4;
typedef __attribute__((ext_vector_type(8))) __bf16 bf16x8;
typedef __attribute__((ext_vector_type(8))) short  short8;

__device__ __forceinline__ unsigned short f2bf(float f) {
  union { float f; unsigned u; } v; v.f = f;
  unsigned u = v.u + 0x7FFFu + ((v.u >> 16) & 1u);   // RNE
  return (unsigned short)(u >> 16);
}
__device__ __forceinline__ float bf2f(unsigned short b) {
  union { unsigned u; float f; } v; v.u = ((unsigned)b) << 16;
  return v.f;
}

// ---------------------------------------------------------------------------
// prep: W1 [256x512] f32 -> W1T [512][256] bf16 ; W2 [512x256] f32 -> W2T [256][512] bf16
// ---------------------------------------------------------------------------
__global__ void prep_kernel(const float* __restrict__ W1, const float* __restrict__ W2,
                            unsigned short* __restrict__ W1T, unsigned short* __restrict__ W2T) {
  int id = blockIdx.x * 256 + threadIdx.x;           // 131072 threads
  {
    int n = id >> 8, k = id & 255;                   // W1T[n][k] = W1[k][n]
    W1T[id] = f2bf(W1[k * DH + n]);
  }
  {
    int n = id >> 9, k = id & 511;                   // W2T[n][k] = W2[k][n]
    W2T[id] = f2bf(W2[k * DO + n]);
  }
}

// ---------------------------------------------------------------------------
// kA: zW = bf16(z @ W1).  16384 x 512, K=256.
// 512 blocks x 512 threads (8 waves); wave w owns 32 cols; XCD-aligned so
// batches 8x..8x+7 are produced on XCD x (kB/kC consume there).
// B frags per-lane contiguous in W1T -> register queue; A tile in 32KB LDS.
// ---------------------------------------------------------------------------
__global__ __launch_bounds__(512, 4) void kA_zw(
    const float* __restrict__ z, const unsigned short* __restrict__ W1T,
    unsigned short* __restrict__ zW) {
  __shared__ __align__(16) unsigned short As[32][64][8];      // [g][row][8] 32KB
  const int tid = threadIdx.x;
  const int xcd = blockIdx.x & 7, idx = blockIdx.x >> 3;
  const int bm = xcd * 32 + (idx >> 1), bn = idx & 1;         // batches 8x..8x+7 on XCD x
  const int row0 = bm * 64, n0b = bn * 256;
  const int wave = tid >> 6, lane = tid & 63, ql = lane >> 4, r16 = lane & 15;
  const int gq = tid >> 8, t8 = tid & 255;
  const int gr = t8 >> 2, sub = t8 & 3;
  const int sxw = (sub << 2) ^ sub;                  // store row swizzle (g&3 = sub)
  const int sxr = (ql << 2) ^ ql;                    // read swizzle (g&3 = ql)

  // per-lane B pointer: frag(nf, s) = 16B at bp + nf*16*DA + s*32
  const unsigned short* bp = W1T + (size_t)(n0b + wave * 32 + r16) * DA + ql * 8;

  bf16x8 bq[2][2];
#pragma unroll
  for (int p = 0; p < 2; ++p)
#pragma unroll
    for (int nf = 0; nf < 2; ++nf)
      bq[p][nf] = *(const bf16x8*)(bp + nf * 16 * DA + p * 32);

  // ---- produce full A tile: z rows f32 -> bf16, swizzled rows ----
  {
    const float* zr = z + (size_t)(row0 + gr) * DA + sub * 8;
#pragma unroll
    for (int cl = 0; cl < 4; ++cl) {
      const int cg = gq * 4 + cl;
      f32x4 a0 = *(const f32x4*)(zr + cg * 32);
      f32x4 a1 = *(const f32x4*)(zr + cg * 32 + 4);
      bf16x8 pk;
#pragma unroll
      for (int j = 0; j < 4; ++j) { pk[j] = (__bf16)a0[j]; pk[4 + j] = (__bf16)a1[j]; }
      *(bf16x8*)&As[cg * 4 + sub][gr ^ sxw][0] = pk;
    }
  }
  __syncthreads();

  f32x4 acc[4][2] = {};
#pragma unroll
  for (int s = 0; s < 8; ++s) {
    bf16x8 afr[4], bfr[2];
#pragma unroll
    for (int mf = 0; mf < 4; ++mf)
      afr[mf] = *(const bf16x8*)&As[s * 4 + ql][(mf * 16 + r16) ^ sxr][0];
#pragma unroll
    for (int nf = 0; nf < 2; ++nf) bfr[nf] = bq[s & 1][nf];
    __builtin_amdgcn_s_setprio(1);
#pragma unroll
    for (int mf = 0; mf < 4; ++mf)
#pragma unroll
      for (int nf = 0; nf < 2; ++nf)
        acc[mf][nf] = __builtin_amdgcn_mfma_f32_16x16x32_bf16(afr[mf], bfr[nf], acc[mf][nf], 0, 0, 0);
    __builtin_amdgcn_s_setprio(0);
    if (s + 2 < 8) {
#pragma unroll
      for (int nf = 0; nf < 2; ++nf)
        bq[s & 1][nf] = *(const bf16x8*)(bp + nf * 16 * DA + (s + 2) * 32);
    }
  }

  const int n0 = n0b + wave * 32;
#pragma unroll
  for (int nf = 0; nf < 2; ++nf) {
    const int col = n0 + nf * 16 + r16;
#pragma unroll
    for (int mf = 0; mf < 4; ++mf)
#pragma unroll
      for (int p = 0; p < 4; ++p)
        zW[(size_t)(row0 + mf * 16 + ql * 4 + p) * DH + col] = f2bf(acc[mf][nf][p]);
  }
}

// ---------------------------------------------------------------------------
// kB: column stats of s = zW[a0]+zW[a1]+zW[a2] (b1 cancels in BN).
// 1024 blocks x 128 rows; chunk swizzle matches kA's producer XCD.
// ---------------------------------------------------------------------------
__global__ __launch_bounds__(256) void kB_stats(
    const unsigned short* __restrict__ zW, const int* __restrict__ tbl,
    float* __restrict__ psum, float* __restrict__ psq) {
  __shared__ int idxs[128][3];
  __shared__ float red1[4][512];
  __shared__ float red2[4][512];
  const int bid = blockIdx.x;
  const int blk = (bid & 7) * (NBS >> 3) + (bid >> 3);   // XCD-chunk swizzle (bijective)
  const int tid = threadIdx.x;
  const int row0 = blk * 128;
  const unsigned short* zWb = zW + (size_t)(row0 >> 11) * NA * DH;

  for (int i = tid; i < 384; i += 256) ((int*)idxs)[i] = tbl[(size_t)row0 * 3 + i];
  __syncthreads();

  const int cc = tid & 63, rg = tid >> 6;
  float s1[8] = {0, 0, 0, 0, 0, 0, 0, 0};
  float s2[8] = {0, 0, 0, 0, 0, 0, 0, 0};
#pragma unroll 8
  for (int i = 0; i < 32; ++i) {
    const int r = rg * 32 + i;
    const unsigned short* p0 = zWb + (size_t)idxs[r][0] * DH + cc * 8;
    const unsigned short* p1 = zWb + (size_t)idxs[r][1] * DH + cc * 8;
    const unsigned short* p2 = zWb + (size_t)idxs[r][2] * DH + cc * 8;
    short8 v0 = *(const short8*)p0;
    short8 v1 = *(const short8*)p1;
    short8 v2 = *(const short8*)p2;
#pragma unroll
    for (int j = 0; j < 8; ++j) {
      float h = bf2f((unsigned short)v0[j]) + bf2f((unsigned short)v1[j]) + bf2f((unsigned short)v2[j]);
      s1[j] += h;
      s2[j] = fmaf(h, h, s2[j]);
    }
  }
#pragma unroll
  for (int j = 0; j < 8; ++j) { red1[rg][cc * 8 + j] = s1[j]; red2[rg][cc * 8 + j] = s2[j]; }
  __syncthreads();
  for (int c = tid; c < 512; c += 256) {
    psum[(size_t)c * NBS + blk] = red1[0][c] + red1[1][c] + red1[2][c] + red1[3][c];
    psq [(size_t)c * NBS + blk] = red2[0][c] + red2[1][c] + red2[2][c] + red2[3][c];
  }
}

// ---------------------------------------------------------------------------
// k2: reduce partials -> a = gamma*rsqrt(var+eps), d = beta - mean*a
// ---------------------------------------------------------------------------
__global__ void k2_stats(const float* __restrict__ psum, const float* __restrict__ psq,
                         const float* __restrict__ gamma, const float* __restrict__ beta,
                         float* __restrict__ coef) {
  const int col = blockIdx.x, lane = threadIdx.x;
  float s1 = 0.f, s2 = 0.f;
  for (int i = lane; i < NBS; i += 64) {
    s1 += psum[(size_t)col * NBS + i];
    s2 += psq [(size_t)col * NBS + i];
  }
#pragma unroll
  for (int d = 1; d < 64; d <<= 1) { s1 += __shfl_xor(s1, d); s2 += __shfl_xor(s2, d); }
  if (lane == 0) {
    const float inv = 1.0f / (float)M;
    float mean = s1 * inv;
    float var  = s2 * inv - mean * mean;
    float a = gamma[col] * rsqrtf(var + 1e-5f);
    coef[col]      = a;
    coef[DH + col] = beta[col] - mean * a;
  }
}

// ---------------------------------------------------------------------------
// kC: out = relu((zW[a0]+zW[a1]+zW[a2])*a + d) @ W2 + b2
// 2048 blocks x 512 threads (8 waves); wave w owns 32 cols; same 64-row tile.
// B in registers (2-deep queue); A per K-half in 32KB LDS; 3 barriers + init.
// ---------------------------------------------------------------------------
__global__ __launch_bounds__(512, 4) void kC_out(
    const unsigned short* __restrict__ zW, const int* __restrict__ tbl,
    const unsigned short* __restrict__ W2T, const float* __restrict__ coef,
    const float* __restrict__ b2, float* __restrict__ out) {
  __shared__ __align__(16) unsigned short As[32][64][8];      // [g][row][8] 32KB
  __shared__ float aC[DH], dC[DH];
  __shared__ int idxs[64][3];

  const int bid = blockIdx.x;
  const int blk = (bid & 7) * (NBC >> 3) + (bid >> 3);     // XCD-chunk swizzle (bijective)
  const int tid = threadIdx.x;
  const int row0 = blk * 64;
  const unsigned short* zWb = zW + (size_t)(row0 >> 11) * NA * DH;

  if (tid < 192) ((int*)idxs)[tid] = tbl[(size_t)row0 * 3 + tid];
  aC[tid] = coef[tid];
  dC[tid] = coef[DH + tid];
  __syncthreads();

  const int wave = tid >> 6, lane = tid & 63, ql = lane >> 4, r16 = lane & 15;
  const int gq = tid >> 8, t8 = tid & 255;
  const int gr = t8 >> 2, sub = t8 & 3;
  const int sxw = (sub << 2) ^ sub;
  const int sxr = (ql << 2) ^ ql;

  const unsigned short* g0p = zWb + (size_t)idxs[gr][0] * DH + sub * 8;
  const unsigned short* g1p = zWb + (size_t)idxs[gr][1] * DH + sub * 8;
  const unsigned short* g2p = zWb + (size_t)idxs[gr][2] * DH + sub * 8;

  // per-lane B pointer: frag(nf, sg) = 16B at bp + nf*16*DH + sg*32
  const unsigned short* bp = W2T + (size_t)(wave * 32 + r16) * DH + ql * 8;

  bf16x8 bq[2][2];
#pragma unroll
  for (int p = 0; p < 2; ++p)
#pragma unroll
    for (int nf = 0; nf < 2; ++nf)
      bq[p][nf] = *(const bf16x8*)(bp + nf * 16 * DH + p * 32);

  f32x4 acc[4][2] = {};

#pragma unroll
  for (int h = 0; h < 2; ++h) {
    if (h) __builtin_amdgcn_s_barrier();             // WAR: all As reads of half 0 done
    // ---- A-phase: gather + affine + relu -> bf16 As tile ----
#pragma unroll
    for (int cl = 0; cl < 4; ++cl) {
      const int coff = h * 256 + (gq * 4 + cl) * 32;
      short8 v0 = *(const short8*)(g0p + coff);
      short8 v1 = *(const short8*)(g1p + coff);
      short8 v2 = *(const short8*)(g2p + coff);
      const int kk = coff + sub * 8;
      f32x4 av0 = *(const f32x4*)&aC[kk];
      f32x4 av1 = *(const f32x4*)&aC[kk + 4];
      f32x4 dv0 = *(const f32x4*)&dC[kk];
      f32x4 dv1 = *(const f32x4*)&dC[kk + 4];
      bf16x8 pk;
#pragma unroll
      for (int j = 0; j < 4; ++j) {
        float h0 = bf2f((unsigned short)v0[j]) + bf2f((unsigned short)v1[j]) + bf2f((unsigned short)v2[j]);
        float f0 = fmaf(h0, av0[j], dv0[j]);
        f0 = f0 > 0.f ? f0 : 0.f;
        pk[j] = (__bf16)f0;
        float h1 = bf2f((unsigned short)v0[4 + j]) + bf2f((unsigned short)v1[4 + j]) + bf2f((unsigned short)v2[4 + j]);
        float f1 = fmaf(h1, av1[j], dv1[j]);
        f1 = f1 > 0.f ? f1 : 0.f;
        pk[4 + j] = (__bf16)f1;
      }
      *(bf16x8*)&As[(gq * 4 + cl) * 4 + sub][gr ^ sxw][0] = pk;
    }
    asm volatile("s_waitcnt lgkmcnt(0)" ::: "memory"); // A stores visible
    __builtin_amdgcn_s_barrier();
    __builtin_amdgcn_sched_barrier(0);                 // no read hoisting above barrier

    // ---- 8 barrier-free MFMA steps; B from register queue ----
#pragma unroll
    for (int s = 0; s < 8; ++s) {
      const int sg = h * 8 + s;
      bf16x8 afr[4], bfr[2];
#pragma unroll
      for (int mf = 0; mf < 4; ++mf)
        afr[mf] = *(const bf16x8*)&As[s * 4 + ql][(mf * 16 + r16) ^ sxr][0];
#pragma unroll
      for (int nf = 0; nf < 2; ++nf) bfr[nf] = bq[sg & 1][nf];
      __builtin_amdgcn_s_setprio(1);
#pragma unroll
      for (int mf = 0; mf < 4; ++mf)
#pragma unroll
        for (int nf = 0; nf < 2; ++nf)
          acc[mf][nf] = __builtin_amdgcn_mfma_f32_16x16x32_bf16(afr[mf], bfr[nf], acc[mf][nf], 0, 0, 0);
      __builtin_amdgcn_s_setprio(0);
      if (sg + 2 < 16) {
#pragma unroll
        for (int nf = 0; nf < 2; ++nf)
          bq[sg & 1][nf] = *(const bf16x8*)(bp + nf * 16 * DH + (sg + 2) * 32);
      }
    }
  }

  const int n0 = wave * 32;
#pragma unroll
  for (int nf = 0; nf < 2; ++nf) {
    const int col = n0 + nf * 16 + r16;
    const float bv = b2[col];
#pragma unroll
    for (int mf = 0; mf < 4; ++mf)
#pragma unroll
      for (int p = 0; p < 4; ++p)
        out[(size_t)(row0 + mf * 16 + ql * 4 + p) * DO + col] = acc[mf][nf][p] + bv;
  }
}

// ---------------------------------------------------------------------------
// workspace layout (bytes):
//   [0,256K)      W1T bf16 [512][256]
//   [256K,512K)   W2T bf16 [256][512]
//   [512K,516K)   coef f32 [1024] (a then d)
//   [2M,4M)       psum f32 [512][1024]
//   [4M,6M)       psumsq f32 [512][1024]
//   [16M,32M)     zW bf16 [16384][512]
// ---------------------------------------------------------------------------
extern "C" void kernel_launch(void* const* d_in, const int* in_sizes, int n_in,
                              void* d_out, int out_size, void* d_ws, size_t ws_size,
                              hipStream_t stream) {
  const float* z     = (const float*)d_in[0];
  const int*   tbl   = (const int*)d_in[1];
  const float* W1    = (const float*)d_in[2];
  // d_in[3] = b1: unused — BatchNorm cancels a constant column shift exactly
  const float* gamma = (const float*)d_in[4];
  const float* beta  = (const float*)d_in[5];
  const float* W2    = (const float*)d_in[6];
  const float* b2    = (const float*)d_in[7];
  float* out = (float*)d_out;

  char* ws = (char*)d_ws;
  unsigned short* W1T  = (unsigned short*)(ws);
  unsigned short* W2T  = (unsigned short*)(ws + (256 << 10));
  float*          coef = (float*)(ws + (512 << 10));
  float*          psum = (float*)(ws + (2 << 20));
  float*          psq  = (float*)(ws + (4 << 20));
  unsigned short* zW   = (unsigned short*)(ws + (16 << 20));

  prep_kernel<<<512, 256, 0, stream>>>(W1, W2, W1T, W2T);
  kA_zw<<<512, 512, 0, stream>>>(z, W1T, zW);
  kB_stats<<<NBS, 256, 0, stream>>>(zW, tbl, psum, psq);
  k2_stats<<<DH, 64, 0, stream>>>(psum, psq, gamma, beta, coef);
  kC_out<<<NBC, 512, 0, stream>>>(zW, tbl, W2T, coef, b2, out);
}